// Round 6
// baseline (181284.998 us; speedup 1.0000x reference)
//
#include <hip/hip_runtime.h>
#include <hip/hip_bf16.h>

// ---------------------------------------------------------------------------
// Attention LSTM decoder (LAS-style), 300 sequential steps.
// R5: ONE persistent kernel (grid 256 x 512) + device-scope atomic barriers
// replaces 1201 graph nodes (theory: dependent-dispatch gaps ~8-10us x4/step
// dominated the 64us/step). Phase bodies identical to the benched R3 code:
//   P1 lstm1 (256 WGs, tid<256 active)  P2 lstm2 (WGs 0-63)
//   P3 attn  (WGs 0-249, all 512 thr)   P4 fin   (WGs 0-63)
// Co-residency: 1 WG/CU (60.7KB LDS, 512 thr) -- all 256 WGs resident.
// ---------------------------------------------------------------------------

constexpr int V_  = 35;
constexpr int E_  = 256;
constexpr int H_  = 512;
constexpr int KS_ = 128;
constexpr int VS_ = 128;
constexpr int NB_ = 64;
constexpr int TT_ = 2000;
constexpr int LL_ = 300;
constexpr int START_ = 33;

// workspace float offsets
constexpr size_t OFF_H1   = 0;        // 2*64*512
constexpr size_t OFF_C1   = 65536;
constexpr size_t OFF_H2   = 98304;    // 2*64*128
constexpr size_t OFF_C2   = 114688;
constexpr size_t OFF_CTX  = 122880;   // state ends 131072
constexpr size_t OFF_PM   = 131072;
constexpr size_t OFF_PS   = 147456;
constexpr size_t OFF_PCTX = 163840;   // 250*64*128 = 2048000
constexpr size_t OFF_BAR  = 2211840;  // 1024 floats (barrier + pad)

__device__ __forceinline__ void fma4(float4& a, const float4 w, const float4 x) {
  a.x = fmaf(w.x, x.x, a.x); a.y = fmaf(w.y, x.y, a.y);
  a.z = fmaf(w.z, x.z, a.z); a.w = fmaf(w.w, x.w, a.w);
}
__device__ __forceinline__ float hsum4(const float4 a) {
  return (a.x + a.y) + (a.z + a.w);
}
__device__ __forceinline__ float sigm(float x) { return 1.0f / (1.0f + expf(-x)); }

// zero state region (128 blocks) + barrier region (block 128)
__global__ void k_zero(float* __restrict__ ws) {
  if (blockIdx.x < 128) {
    int i = blockIdx.x * 256 + threadIdx.x;
    *(float4*)&ws[(size_t)i * 4] = make_float4(0.f, 0.f, 0.f, 0.f);
  } else {
    *(float4*)&ws[OFF_BAR + (size_t)threadIdx.x * 4] =
        make_float4(0.f, 0.f, 0.f, 0.f);
  }
}

// grid-wide barrier: monotonic counter, agent scope. Spin-capped: a failure
// corrupts results (caught by validation) instead of hanging the harness.
__device__ __forceinline__ void gbar(unsigned* bar, unsigned target) {
  __syncthreads();
  if (threadIdx.x == 0) {
    __threadfence();  // release all prior global writes (agent scope)
    __hip_atomic_fetch_add(bar, 1u, __ATOMIC_RELEASE, __HIP_MEMORY_SCOPE_AGENT);
    unsigned spins = 0;
    while (__hip_atomic_load(bar, __ATOMIC_ACQUIRE, __HIP_MEMORY_SCOPE_AGENT) <
           target) {
      __builtin_amdgcn_s_sleep(2);
      if (++spins > (1u << 18)) break;
    }
    __threadfence();  // acquire: invalidate stale L1/L2 before phase reads
  }
  __syncthreads();
}

struct SmemG {  // lstm phases: 60,736 B
  float Wc[16 * 132];
  float Xs[32 * 132];
  float pp[16 * 520];
  float gbuf[512];
  float bias[16];
};
struct SmemA {  // attn phase: 36,096 B
  float h2s[64 * 132];
  float es[64 * 9];
};
struct SmemF {  // fin phase: 4 KB
  float red[256];
  float ews[256];
  float cbuf[256];
  float cat[256];
};
union __align__(16) Smem {
  SmemG g;
  SmemA a;
  SmemF f;
};

__global__ __launch_bounds__(512, 1) void k_persist(
    const float* __restrict__ key, const float* __restrict__ values,
    const int* __restrict__ lens, const int* __restrict__ text,
    const float* __restrict__ emb, const float* __restrict__ Wih1,
    const float* __restrict__ Whh1, const float* __restrict__ bih1,
    const float* __restrict__ bhh1, const float* __restrict__ Wih2,
    const float* __restrict__ Whh2, const float* __restrict__ bih2,
    const float* __restrict__ bhh2, const float* __restrict__ bout,
    float* __restrict__ out, float* __restrict__ ws) {
  __shared__ Smem sm;
  float* h1buf = ws + OFF_H1;
  float* c1    = ws + OFF_C1;
  float* h2buf = ws + OFF_H2;
  float* c2    = ws + OFF_C2;
  float* ctx   = ws + OFF_CTX;
  float* pm    = ws + OFF_PM;
  float* ps    = ws + OFF_PS;
  float* pctx  = ws + OFF_PCTX;
  unsigned* bar = (unsigned*)(ws + OFF_BAR);

  const int wg = blockIdx.x;
  const int tid = threadIdx.x;
  unsigned bk = 0;

  for (int t = 0; t < LL_; ++t) {
    // ---------------- P1: lstm1 (all 256 WGs; tid<256 active) -------------
    {
      const bool act = tid < 256;
      const int mtile = wg >> 1, nhalf = wg & 1;
      const int u0 = mtile * 4;
      const int nbase = nhalf * 32;
      const float* h1in = h1buf + (t & 1) * (NB_ * H_);
      float* h1out = h1buf + ((t & 1) ^ 1) * (NB_ * H_);

      if (tid < 16) {
        int g = tid >> 2, du = tid & 3;
        int grow = g * H_ + u0 + du;
        sm.g.bias[tid] = bih1[grow] + bhh1[grow];
      }
      const int ng = tid & 3, rg = (tid >> 2) & 3, ks = tid >> 4;
      float4 acc[4][8];
      if (act) {
#pragma unroll
        for (int j = 0; j < 4; ++j)
#pragma unroll
          for (int i = 0; i < 8; ++i) acc[j][i] = make_float4(0.f, 0.f, 0.f, 0.f);
      }
      for (int c = 0; c < 7; ++c) {
        __syncthreads();
        if (act) {
#pragma unroll
          for (int i = 0; i < 2; ++i) {
            int f4 = i * 256 + tid;
            int rl = f4 >> 5, kq = f4 & 31;
            int g = rl >> 2, du = rl & 3;
            int grow = g * H_ + u0 + du;
            int k = c * 128 + kq * 4;
            float4 v;
            if (k < 384) v = *(const float4*)&Wih1[grow * 384 + k];
            else         v = *(const float4*)&Whh1[grow * 512 + (k - 384)];
            *(float4*)&sm.g.Wc[rl * 132 + kq * 4] = v;
          }
#pragma unroll
          for (int i = 0; i < 4; ++i) {
            int f4 = i * 256 + tid;
            int nl = f4 >> 5, kq = f4 & 31;
            int n = nbase + nl;
            int k = c * 128 + kq * 4;
            float4 v;
            if (c < 2) {
              int tok = (t == 0) ? START_ : text[n * LL_ + t - 1];
              v = *(const float4*)&emb[tok * E_ + k];
            } else if (c == 2) {
              v = *(const float4*)&ctx[n * VS_ + (k - 256)];
            } else {
              v = *(const float4*)&h1in[n * H_ + (k - 384)];
            }
            *(float4*)&sm.g.Xs[nl * 132 + kq * 4] = v;
          }
        }
        __syncthreads();
        if (act) {
#pragma unroll
          for (int it = 0; it < 2; ++it) {
            int kl = (it * 16 + ks) * 4;
            float4 w[4], x[8];
#pragma unroll
            for (int j = 0; j < 4; ++j)
              w[j] = *(const float4*)&sm.g.Wc[(rg * 4 + j) * 132 + kl];
#pragma unroll
            for (int i = 0; i < 8; ++i)
              x[i] = *(const float4*)&sm.g.Xs[(ng + 4 * i) * 132 + kl];
#pragma unroll
            for (int j = 0; j < 4; ++j)
#pragma unroll
              for (int i = 0; i < 8; ++i) fma4(acc[j][i], w[j], x[i]);
          }
        }
      }
      if (act) {
#pragma unroll
        for (int j = 0; j < 4; ++j)
#pragma unroll
          for (int i = 0; i < 8; ++i)
            sm.g.pp[ks * 520 + (rg * 4 + j) * 32 + ng + 4 * i] = hsum4(acc[j][i]);
      }
      __syncthreads();
      if (act) {
#pragma unroll
        for (int rep = 0; rep < 2; ++rep) {
          int o = rep * 256 + tid;
          float s = 0.f;
#pragma unroll
          for (int kk = 0; kk < 16; ++kk) s += sm.g.pp[kk * 520 + o];
          sm.g.gbuf[o] = s + sm.g.bias[o >> 5];
        }
      }
      __syncthreads();
      if (tid < 128) {
        int du = tid & 3, nl = tid >> 2;
        int n = nbase + nl, u = u0 + du;
        float ig = sm.g.gbuf[(0 * 4 + du) * 32 + nl];
        float fg = sm.g.gbuf[(1 * 4 + du) * 32 + nl];
        float gg = sm.g.gbuf[(2 * 4 + du) * 32 + nl];
        float og = sm.g.gbuf[(3 * 4 + du) * 32 + nl];
        float cn = sigm(fg) * c1[n * H_ + u] + sigm(ig) * tanhf(gg);
        c1[n * H_ + u] = cn;
        h1out[n * H_ + u] = sigm(og) * tanhf(cn);
      }
    }
    gbar(bar, 256u * (++bk));

    // ---------------- P2: lstm2 (WGs 0-63; tid<256 active) ----------------
    if (wg < 64) {
      const bool act = tid < 256;
      const int mtile = wg >> 1, nhalf = wg & 1;
      const int u0 = mtile * 4;
      const int nbase = nhalf * 32;
      const float* h1t = h1buf + ((t & 1) ^ 1) * (NB_ * H_);
      const float* h2p = h2buf + (t & 1) * (NB_ * KS_);
      float* h2o = h2buf + ((t & 1) ^ 1) * (NB_ * KS_);

      if (tid < 16) {
        int g = tid >> 2, du = tid & 3;
        int grow = g * KS_ + u0 + du;
        sm.g.bias[tid] = bih2[grow] + bhh2[grow];
      }
      const int ng = tid & 3, rg = (tid >> 2) & 3, ks = tid >> 4;
      float4 acc[4][8];
      if (act) {
#pragma unroll
        for (int j = 0; j < 4; ++j)
#pragma unroll
          for (int i = 0; i < 8; ++i) acc[j][i] = make_float4(0.f, 0.f, 0.f, 0.f);
      }
      for (int c = 0; c < 5; ++c) {
        __syncthreads();
        if (act) {
#pragma unroll
          for (int i = 0; i < 2; ++i) {
            int f4 = i * 256 + tid;
            int rl = f4 >> 5, kq = f4 & 31;
            int g = rl >> 2, du = rl & 3;
            int grow = g * KS_ + u0 + du;
            int k = c * 128 + kq * 4;
            float4 v;
            if (k < 512) v = *(const float4*)&Wih2[grow * 512 + k];
            else         v = *(const float4*)&Whh2[grow * 128 + (k - 512)];
            *(float4*)&sm.g.Wc[rl * 132 + kq * 4] = v;
          }
#pragma unroll
          for (int i = 0; i < 4; ++i) {
            int f4 = i * 256 + tid;
            int nl = f4 >> 5, kq = f4 & 31;
            int n = nbase + nl;
            int k = c * 128 + kq * 4;
            float4 v;
            if (c < 4) v = *(const float4*)&h1t[n * H_ + k];
            else       v = *(const float4*)&h2p[n * KS_ + (k - 512)];
            *(float4*)&sm.g.Xs[nl * 132 + kq * 4] = v;
          }
        }
        __syncthreads();
        if (act) {
#pragma unroll
          for (int it = 0; it < 2; ++it) {
            int kl = (it * 16 + ks) * 4;
            float4 w[4], x[8];
#pragma unroll
            for (int j = 0; j < 4; ++j)
              w[j] = *(const float4*)&sm.g.Wc[(rg * 4 + j) * 132 + kl];
#pragma unroll
            for (int i = 0; i < 8; ++i)
              x[i] = *(const float4*)&sm.g.Xs[(ng + 4 * i) * 132 + kl];
#pragma unroll
            for (int j = 0; j < 4; ++j)
#pragma unroll
              for (int i = 0; i < 8; ++i) fma4(acc[j][i], w[j], x[i]);
          }
        }
      }
      if (act) {
#pragma unroll
        for (int j = 0; j < 4; ++j)
#pragma unroll
          for (int i = 0; i < 8; ++i)
            sm.g.pp[ks * 520 + (rg * 4 + j) * 32 + ng + 4 * i] = hsum4(acc[j][i]);
      }
      __syncthreads();
      if (act) {
#pragma unroll
        for (int rep = 0; rep < 2; ++rep) {
          int o = rep * 256 + tid;
          float s = 0.f;
#pragma unroll
          for (int kk = 0; kk < 16; ++kk) s += sm.g.pp[kk * 520 + o];
          sm.g.gbuf[o] = s + sm.g.bias[o >> 5];
        }
      }
      __syncthreads();
      if (tid < 128) {
        int du = tid & 3, nl = tid >> 2;
        int n = nbase + nl, u = u0 + du;
        float ig = sm.g.gbuf[(0 * 4 + du) * 32 + nl];
        float fg = sm.g.gbuf[(1 * 4 + du) * 32 + nl];
        float gg = sm.g.gbuf[(2 * 4 + du) * 32 + nl];
        float og = sm.g.gbuf[(3 * 4 + du) * 32 + nl];
        float cn = sigm(fg) * c2[n * KS_ + u] + sigm(ig) * tanhf(gg);
        c2[n * KS_ + u] = cn;
        h2o[n * KS_ + u] = sigm(og) * tanhf(cn);
      }
    }
    gbar(bar, 256u * (++bk));

    // ---------------- P3: attn (WGs 0-249; all 512 threads) ---------------
    if (wg < 250) {
      const int s = wg;
      const int t0 = s * 8;
      const float* h2 = h2buf + ((t & 1) ^ 1) * (NB_ * KS_);
#pragma unroll
      for (int i = 0; i < 4; ++i) {
        int f4 = i * 512 + tid;
        int n = f4 >> 5, q = f4 & 31;
        *(float4*)&sm.a.h2s[n * 132 + q * 4] = *(const float4*)&h2[n * KS_ + q * 4];
      }
      __syncthreads();
      const int wv = tid >> 6;
      const int ln = tid & 63;
      const int half = ln >> 5;
      const int ch = ln & 31;
      for (int i = 0; i < 8; ++i) {
        int n = wv * 8 + i;
        float4 hc = *(const float4*)&sm.a.h2s[n * 132 + ch * 4];
#pragma unroll
        for (int rp = 0; rp < 4; ++rp) {
          int j = rp * 2 + half;
          float4 kv = *(const float4*)&key[((size_t)n * TT_ + t0 + j) * KS_ + ch * 4];
          float d = kv.x * hc.x + kv.y * hc.y + kv.z * hc.z + kv.w * hc.w;
          d += __shfl_xor(d, 16);
          d += __shfl_xor(d, 8);
          d += __shfl_xor(d, 4);
          d += __shfl_xor(d, 2);
          d += __shfl_xor(d, 1);
          if (ch == 0) sm.a.es[n * 9 + j] = d;
        }
      }
      __syncthreads();
      if (tid < 64) {
        int n = tid;
        int len = lens[n];
        float ev[8];
        float m = -1e30f;
#pragma unroll
        for (int j = 0; j < 8; ++j) {
          float e = (t0 + j >= len) ? -1e9f : sm.a.es[n * 9 + j];
          ev[j] = e;
          m = fmaxf(m, e);
        }
        float ssum = 0.f;
#pragma unroll
        for (int j = 0; j < 8; ++j) {
          float p = expf(ev[j] - m);
          sm.a.es[n * 9 + j] = p;
          ssum += p;
        }
        pm[n * 256 + s] = m;
        ps[n * 256 + s] = ssum;
      }
      __syncthreads();
      for (int i = 0; i < 8; ++i) {
        int n = wv * 8 + i;
        float4 a = make_float4(0.f, 0.f, 0.f, 0.f);
#pragma unroll
        for (int it2 = 0; it2 < 4; ++it2) {
          int j = it2 * 2 + half;
          float p = sm.a.es[n * 9 + j];
          float4 vv =
              *(const float4*)&values[((size_t)n * TT_ + t0 + j) * VS_ + ch * 4];
          a.x = fmaf(p, vv.x, a.x); a.y = fmaf(p, vv.y, a.y);
          a.z = fmaf(p, vv.z, a.z); a.w = fmaf(p, vv.w, a.w);
        }
        a.x += __shfl_xor(a.x, 32);
        a.y += __shfl_xor(a.y, 32);
        a.z += __shfl_xor(a.z, 32);
        a.w += __shfl_xor(a.w, 32);
        if (half == 0)
          *(float4*)&pctx[((size_t)s * 64 + n) * 128 + ch * 4] = a;
      }
    }
    gbar(bar, 256u * (++bk));

    // ---------------- P4: fin (WGs 0-63; tid<256 active) ------------------
    if (wg < 64) {
      const int n = wg;
      const bool act = tid < 256;
      const float* h2 = h2buf + ((t & 1) ^ 1) * (NB_ * KS_);
      float m = -1e30f;
      if (act) {
        if (tid < 250) m = pm[n * 256 + tid];
        sm.f.red[tid] = m;
      }
      __syncthreads();
      for (int w = 128; w > 0; w >>= 1) {
        if (tid < w) sm.f.red[tid] = fmaxf(sm.f.red[tid], sm.f.red[tid + w]);
        __syncthreads();
      }
      float M = sm.f.red[0];
      __syncthreads();
      float wv2 = 0.f;
      if (act) {
        if (tid < 250) {
          float e = expf(m - M);
          sm.f.ews[tid] = e;
          wv2 = e * ps[n * 256 + tid];
        } else {
          sm.f.ews[tid] = 0.f;
        }
        sm.f.red[tid] = wv2;
      }
      __syncthreads();
      for (int w = 128; w > 0; w >>= 1) {
        if (tid < w) sm.f.red[tid] += sm.f.red[tid + w];
        __syncthreads();
      }
      float S = sm.f.red[0];
      if (act) {
        int v = tid & 127, sh = tid >> 7;
        float a = 0.f;
        for (int i = 0; i < 125; ++i) {
          int sl = sh * 125 + i;
          a = fmaf(sm.f.ews[sl], pctx[((size_t)sl * 64 + n) * 128 + v], a);
        }
        sm.f.cbuf[sh * 128 + v] = a;
      }
      __syncthreads();
      if (tid < 128) {
        float cv = (sm.f.cbuf[tid] + sm.f.cbuf[128 + tid]) / S;
        ctx[n * 128 + tid] = cv;
        sm.f.cat[128 + tid] = cv;
        sm.f.cat[tid] = h2[n * KS_ + tid];
      }
      __syncthreads();
      if (tid < V_) {
        float a = bout[tid];
        const float* er = emb + tid * E_;
#pragma unroll 8
        for (int q = 0; q < 64; ++q) {
          float4 ev = *(const float4*)&er[q * 4];
          a = fmaf(ev.x, sm.f.cat[q * 4 + 0], a);
          a = fmaf(ev.y, sm.f.cat[q * 4 + 1], a);
          a = fmaf(ev.z, sm.f.cat[q * 4 + 2], a);
          a = fmaf(ev.w, sm.f.cat[q * 4 + 3], a);
        }
        out[((size_t)n * LL_ + t) * V_ + tid] = a;
      }
    }
    gbar(bar, 256u * (++bk));
  }
}

extern "C" void kernel_launch(void* const* d_in, const int* in_sizes, int n_in,
                              void* d_out, int out_size, void* d_ws,
                              size_t ws_size, hipStream_t stream) {
  const float* key    = (const float*)d_in[0];
  const float* values = (const float*)d_in[1];
  const int*   lens   = (const int*)d_in[2];
  const int*   text   = (const int*)d_in[3];
  const float* emb    = (const float*)d_in[4];
  const float* Wih1   = (const float*)d_in[5];
  const float* Whh1   = (const float*)d_in[6];
  const float* bih1   = (const float*)d_in[7];
  const float* bhh1   = (const float*)d_in[8];
  const float* Wih2   = (const float*)d_in[9];
  const float* Whh2   = (const float*)d_in[10];
  const float* bih2   = (const float*)d_in[11];
  const float* bhh2   = (const float*)d_in[12];
  const float* bout   = (const float*)d_in[13];
  float* out = (float*)d_out;
  float* ws = (float*)d_ws;

  hipLaunchKernelGGL(k_zero, dim3(129), dim3(256), 0, stream, ws);
  hipLaunchKernelGGL(k_persist, dim3(256), dim3(512), 0, stream,
                     key, values, lens, text, emb, Wih1, Whh1, bih1, bhh1,
                     Wih2, Whh2, bih2, bhh2, bout, out, ws);
}